// Round 1
// baseline (132.283 us; speedup 1.0000x reference)
//
#include <hip/hip_runtime.h>
#include <hip/hip_bf16.h>
#include <cstdint>

typedef __bf16 bf16x8 __attribute__((ext_vector_type(8)));
typedef float floatx4 __attribute__((ext_vector_type(4)));

#define M_TOTAL 4096
#define C_DIM   256

// ws layout (bytes). Total ~8.02 MB.
#define OFF_X     (0u)
#define OFF_Y     (2u*1024*1024)
#define OFF_PMAX  (4u*1024*1024)
#define OFF_PSUM  (5u*1024*1024)
#define OFF_PBC   (6u*1024*1024)
#define OFF_DIAG  (7u*1024*1024)
#define OFF_LPART (OFF_DIAG + 16384u)
#define OFF_CPART (OFF_LPART + 64u)

// ---------------------------------------------------------------------------
// K0: pred/gt (B,N,C,H,W) fp32 -> row-major (M=4096, C=256) bf16 (RNE).
// X[m][c] = in[(m>>4)*4096 + c*16 + (m&15)]
// ---------------------------------------------------------------------------
__global__ __launch_bounds__(256) void transpose_cast(
    const float* __restrict__ pred, const float* __restrict__ gt,
    unsigned short* __restrict__ Xbf, unsigned short* __restrict__ Ybf) {
  int T = blockIdx.x * 256 + threadIdx.x;   // 0 .. 262143
  const float* src;
  unsigned short* dst;
  int Th = T;
  if (T < 131072) { src = pred; dst = Xbf; }
  else            { src = gt;   dst = Ybf; Th = T - 131072; }
  int m  = Th >> 5;        // row (0..4095)
  int c8 = Th & 31;        // 8-wide c chunk
  int slab = m >> 4, hw = m & 15;
  const float* base = src + slab * 4096 + hw;
  unsigned int packed[4];
  #pragma unroll
  for (int jj = 0; jj < 4; ++jj) {
    unsigned int lohi[2];
    #pragma unroll
    for (int k = 0; k < 2; ++k) {
      int c = c8 * 8 + jj * 2 + k;
      float f = base[c * 16];
      unsigned int u = __float_as_uint(f);
      lohi[k] = (u + 0x7FFFu + ((u >> 16) & 1u)) >> 16;   // RNE to bf16
    }
    packed[jj] = lohi[0] | (lohi[1] << 16);
  }
  uint4 v;
  v.x = packed[0]; v.y = packed[1]; v.z = packed[2]; v.w = packed[3];
  *reinterpret_cast<uint4*>(dst + m * 256 + c8 * 8) = v;
}

// ---------------------------------------------------------------------------
// K1: 64x64 tile of lossmat = X @ Y^T via mfma_f32_16x16x32_bf16, full K=256
// in LDS (XOR-swizzled 16B chunks). Each wave owns 16 rows x 64 cols, computes
// fused per-row partials: rowmax, sum-exp(v-max), argmax col; diagonal blocks
// also extract lossmat[i,i].
// ---------------------------------------------------------------------------
__global__ __launch_bounds__(256) void gemm_softmax_partial(
    const unsigned short* __restrict__ Xbf, const unsigned short* __restrict__ Ybf,
    float* __restrict__ pmax, float* __restrict__ psum, int* __restrict__ pbc,
    float* __restrict__ diag) {
  __shared__ __align__(16) unsigned short As[64 * 256];  // 32 KB
  __shared__ __align__(16) unsigned short Bs[64 * 256];  // 32 KB
  const int t  = threadIdx.x;
  const int bR = blockIdx.x, bC = blockIdx.y;
  const unsigned short* Ag = Xbf + bR * 64 * 256;   // contiguous 32 KB
  const unsigned short* Bg = Ybf + bC * 64 * 256;

  // stage both tiles; LDS chunk (r, j) holds global chunk (r, j ^ (r&7))
  #pragma unroll
  for (int it = 0; it < 8; ++it) {
    int cid = it * 256 + t;          // 0..2047  (16B chunks)
    int r = cid >> 5, j = cid & 31;
    int jg = j ^ (r & 7);
    *reinterpret_cast<uint4*>(As + r * 256 + j * 8) =
        *reinterpret_cast<const uint4*>(Ag + r * 256 + jg * 8);
    *reinterpret_cast<uint4*>(Bs + r * 256 + j * 8) =
        *reinterpret_cast<const uint4*>(Bg + r * 256 + jg * 8);
  }
  __syncthreads();

  const int wave = t >> 6, lane = t & 63;
  const int quad = lane >> 4, lc = lane & 15;
  floatx4 zero = {0.f, 0.f, 0.f, 0.f};
  floatx4 acc[4] = {zero, zero, zero, zero};
  const int arow = wave * 16 + lc;       // A row (tile-local) this lane feeds
  const int asw  = arow & 7;

  #pragma unroll
  for (int kk = 0; kk < 8; ++kk) {
    int c = kk * 4 + quad;               // 16B k-chunk index (k = c*8..c*8+7)
    bf16x8 a = *reinterpret_cast<const bf16x8*>(As + arow * 256 + (c ^ asw) * 8);
    #pragma unroll
    for (int f = 0; f < 4; ++f) {
      int brow = f * 16 + lc;            // Y row == lossmat col (tile-local)
      bf16x8 b = *reinterpret_cast<const bf16x8*>(Bs + brow * 256 + (c ^ (brow & 7)) * 8);
      acc[f] = __builtin_amdgcn_mfma_f32_16x16x32_bf16(a, b, acc[f], 0, 0, 0);
    }
  }

  // C/D layout: value acc[f][r] is lossmat row (wave*16 + quad*4 + r),
  //             col (f*16 + lc) [tile-local].
  if (bR == bC) {
    #pragma unroll
    for (int f = 0; f < 4; ++f) {
      int coll  = f * 16 + lc;
      int rbase = wave * 16 + quad * 4;
      if (coll >= rbase && coll < rbase + 4)
        diag[bR * 64 + coll] = acc[f][coll - rbase];
    }
  }

  #pragma unroll
  for (int r = 0; r < 4; ++r) {
    // row max over this block's 64 cols (also the argmax value)
    float m = fmaxf(fmaxf(acc[0][r], acc[1][r]), fmaxf(acc[2][r], acc[3][r]));
    #pragma unroll
    for (int s = 1; s < 16; s <<= 1) m = fmaxf(m, __shfl_xor(m, s, 64));
    float ssum = 0.f;
    float bv = -3.4e38f; int bc = 0;
    #pragma unroll
    for (int f = 0; f < 4; ++f) {
      float v = acc[f][r];
      ssum += __expf(v - m);
      int col = bC * 64 + f * 16 + lc;
      if (v > bv) { bv = v; bc = col; }
    }
    #pragma unroll
    for (int s = 1; s < 16; s <<= 1) ssum += __shfl_xor(ssum, s, 64);
    #pragma unroll
    for (int s = 1; s < 16; s <<= 1) {
      float ov = __shfl_xor(bv, s, 64);
      int   oc = __shfl_xor(bc, s, 64);
      if (ov > bv || (ov == bv && oc < bc)) { bv = ov; bc = oc; }
    }
    if (lc == 0) {
      int gr = bR * 64 + wave * 16 + quad * 4 + r;
      int p  = gr * 64 + bC;
      pmax[p] = m; psum[p] = ssum; pbc[p] = bc;
    }
  }
}

// ---------------------------------------------------------------------------
// K2: combine 64 column-block partials per row -> per-row loss & correct,
// reduce over 256 rows/block -> 16 block partials.
// ---------------------------------------------------------------------------
__global__ __launch_bounds__(256) void combine_rows(
    const float* __restrict__ pmax, const float* __restrict__ psum,
    const int* __restrict__ pbc, const float* __restrict__ diag,
    float* __restrict__ lpart, float* __restrict__ cpart) {
  int row = blockIdx.x * 256 + threadIdx.x;
  const float* pm = pmax + row * 64;
  const float* ps = psum + row * 64;
  const int*   pc = pbc  + row * 64;
  float M = -3.4e38f;
  #pragma unroll 8
  for (int b = 0; b < 64; ++b) M = fmaxf(M, pm[b]);
  float S = 0.f;
  #pragma unroll 8
  for (int b = 0; b < 64; ++b) S += ps[b] * __expf(pm[b] - M);
  float bv = -3.4e38f; int bc = -1;
  #pragma unroll 8
  for (int b = 0; b < 64; ++b) {
    float v = pm[b];                    // block max == block argmax value
    if (v > bv) { bv = v; bc = pc[b]; } // ascending b => first-index tiebreak
  }
  float lossr = logf(S) + M - diag[row];
  float corr  = (bc == row) ? 1.f : 0.f;
  #pragma unroll
  for (int s = 1; s < 64; s <<= 1) {
    lossr += __shfl_xor(lossr, s, 64);
    corr  += __shfl_xor(corr,  s, 64);
  }
  __shared__ float ls[4], cs[4];
  int wave = threadIdx.x >> 6, lane = threadIdx.x & 63;
  if (lane == 0) { ls[wave] = lossr; cs[wave] = corr; }
  __syncthreads();
  if (threadIdx.x == 0) {
    lpart[blockIdx.x] = ls[0] + ls[1] + ls[2] + ls[3];
    cpart[blockIdx.x] = cs[0] + cs[1] + cs[2] + cs[3];
  }
}

// ---------------------------------------------------------------------------
// K3: final reduce of 16 partials -> (loss, acc)
// ---------------------------------------------------------------------------
__global__ void finalize(const float* __restrict__ lpart,
                         const float* __restrict__ cpart,
                         float* __restrict__ out) {
  int t = threadIdx.x;
  float l = (t < 16) ? lpart[t] : 0.f;
  float c = (t < 16) ? cpart[t] : 0.f;
  #pragma unroll
  for (int s = 1; s < 16; s <<= 1) {
    l += __shfl_xor(l, s, 64);
    c += __shfl_xor(c, s, 64);
  }
  if (t == 0) {
    out[0] = l * (1.f / 4096.f);
    out[1] = c * (100.f / 4096.f);
  }
}

extern "C" void kernel_launch(void* const* d_in, const int* in_sizes, int n_in,
                              void* d_out, int out_size, void* d_ws, size_t ws_size,
                              hipStream_t stream) {
  const float* pred = (const float*)d_in[0];
  const float* gt   = (const float*)d_in[1];
  char* w = (char*)d_ws;
  unsigned short* Xbf = (unsigned short*)(w + OFF_X);
  unsigned short* Ybf = (unsigned short*)(w + OFF_Y);
  float* pmax  = (float*)(w + OFF_PMAX);
  float* psum  = (float*)(w + OFF_PSUM);
  int*   pbc   = (int*)  (w + OFF_PBC);
  float* diag  = (float*)(w + OFF_DIAG);
  float* lpart = (float*)(w + OFF_LPART);
  float* cpart = (float*)(w + OFF_CPART);
  float* out   = (float*)d_out;

  transpose_cast<<<1024, 256, 0, stream>>>(pred, gt, Xbf, Ybf);
  dim3 g1(64, 64);
  gemm_softmax_partial<<<g1, 256, 0, stream>>>(Xbf, Ybf, pmax, psum, pbc, diag);
  combine_rows<<<16, 256, 0, stream>>>(pmax, psum, pbc, diag, lpart, cpart);
  finalize<<<1, 64, 0, stream>>>(lpart, cpart, out);
}

// Round 2
// 93.799 us; speedup vs baseline: 1.4103x; 1.4103x over previous
//
#include <hip/hip_runtime.h>
#include <cstdint>

typedef __bf16 bf16x8 __attribute__((ext_vector_type(8)));
typedef float floatx4 __attribute__((ext_vector_type(4)));

// M = 4096 rows, C(K) = 256. GEMM block tile 128x128, K-slab 64.
//
// Staged global layout (produced by transpose_stage, consumed by GEMM):
//   Xs[rb(32)][s(4)][kk(2)][rowhi(8)][quad(4)][rowlo(16)][8 bf16]
// holding element X[row = rb*128+rowhi*16+rowlo][k = s*64+kk*32+quad*8+j].
// This is exactly the LDS image for conflict-free lane-linear ds_read_b128
// fragment reads AND lane-linear global_load_lds staging.

#define OFF_X     (0u)
#define OFF_Y     (2u*1024*1024)
#define OFF_PMAX  (4u*1024*1024)
#define OFF_PSUM  (5u*1024*1024)
#define OFF_DIAG  (6u*1024*1024)
#define OFF_LPART (OFF_DIAG + 16384u)
#define OFF_CPART (OFF_LPART + 256u)

#define AS1C(p) ((const __attribute__((address_space(1))) void*)(const void*)(p))
#define AS3(p)  ((__attribute__((address_space(3))) void*)(void*)(p))

// ---------------------------------------------------------------------------
// K0: pred/gt (B,N,C,H,W) fp32 -> staged bf16 layout. One block per slab
// (one (b,n) pair = 16 rows x 256 c, 16 KB contiguous input).
// Reads: for output chunk (s,kk,quad,rowlo): 8 floats at
//   src[slab*4096 + (k0+j)*16 + rowlo]  -- across a wave these are 4 full
// 64B lines per j-instruction (fully coalesced). Writes: 16B per chunk.
// ---------------------------------------------------------------------------
__global__ __launch_bounds__(256) void transpose_stage(
    const float* __restrict__ pred, const float* __restrict__ gt,
    unsigned short* __restrict__ Xs, unsigned short* __restrict__ Ys) {
  int blk = blockIdx.x;
  const float* src;
  unsigned short* dst;
  int slab;
  if (blk < 256) { src = pred; dst = Xs; slab = blk; }
  else           { src = gt;   dst = Ys; slab = blk - 256; }
  const float* sb = src + slab * 4096;
  const int rb = slab >> 3, rowhi = slab & 7;
  const int t = threadIdx.x;
  #pragma unroll
  for (int half = 0; half < 2; ++half) {
    int c_ = half * 256 + t;                 // chunk id within slab, 0..511
    int rowlo = c_ & 15;
    int quad  = (c_ >> 4) & 3;
    int kk    = (c_ >> 6) & 1;
    int s     = c_ >> 7;
    int k0 = s * 64 + kk * 32 + quad * 8;
    unsigned int packed[4];
    #pragma unroll
    for (int jj = 0; jj < 4; ++jj) {
      unsigned int lohi[2];
      #pragma unroll
      for (int e = 0; e < 2; ++e) {
        float f = sb[(k0 + jj * 2 + e) * 16 + rowlo];
        unsigned int u = __float_as_uint(f);
        lohi[e] = (u + 0x7FFFu + ((u >> 16) & 1u)) >> 16;   // RNE -> bf16
      }
      packed[jj] = lohi[0] | (lohi[1] << 16);
    }
    unsigned short* o = dst + rb * 32768 +
        (unsigned)(s * 1024 + kk * 512 + rowhi * 64 + quad * 16 + rowlo) * 8;
    uint4 v; v.x = packed[0]; v.y = packed[1]; v.z = packed[2]; v.w = packed[3];
    *reinterpret_cast<uint4*>(o) = v;
  }
}

// ---------------------------------------------------------------------------
// K1: lossmat tile (128x128) = X @ Y^T, mfma_f32_16x16x32_bf16.
// 4 waves as 2x2 (rg,cg), wave tile 64x64 = 4x4 fragments.
// K streamed in 4 slabs of 64 through 32 KB LDS via global_load_lds(16B).
// Fused epilogue: per-row (max, sum-exp) partials per 64-col group; diagonal
// blocks also write lossmat[i,i].
// ---------------------------------------------------------------------------
__global__ __launch_bounds__(256) void gemm_softmax_partial(
    const unsigned short* __restrict__ Xs, const unsigned short* __restrict__ Ys,
    float* __restrict__ pmax, float* __restrict__ psum, float* __restrict__ diag) {
  __shared__ __align__(16) unsigned short As[8192];  // 16 KB: 128 rows x 64 k
  __shared__ __align__(16) unsigned short Bs[8192];
  const int t = threadIdx.x;
  const int wave = t >> 6, lane = t & 63;
  const int rg = wave >> 1, cg = wave & 1;
  const int bR = blockIdx.x, bC = blockIdx.y;
  const unsigned short* Ag = Xs + bR * 32768;
  const unsigned short* Bg = Ys + bC * 32768;

  floatx4 acc[4][4];
  const floatx4 zero = {0.f, 0.f, 0.f, 0.f};
  #pragma unroll
  for (int i = 0; i < 4; ++i)
    #pragma unroll
    for (int j = 0; j < 4; ++j) acc[i][j] = zero;

  for (int s = 0; s < 4; ++s) {
    #pragma unroll
    for (int it = 0; it < 4; ++it) {
      int chunk = it * 256 + t;        // lane-linear: 16B per thread
      __builtin_amdgcn_global_load_lds(AS1C(Ag + s * 8192 + chunk * 8),
                                       AS3(As + chunk * 8), 16, 0, 0);
      __builtin_amdgcn_global_load_lds(AS1C(Bg + s * 8192 + chunk * 8),
                                       AS3(Bs + chunk * 8), 16, 0, 0);
    }
    __syncthreads();
    #pragma unroll
    for (int kk = 0; kk < 2; ++kk) {
      bf16x8 a[4], b[4];
      #pragma unroll
      for (int fr = 0; fr < 4; ++fr)
        a[fr] = *reinterpret_cast<const bf16x8*>(
            As + (unsigned)(kk * 512 + (rg * 4 + fr) * 64 + lane) * 8);
      #pragma unroll
      for (int fc = 0; fc < 4; ++fc)
        b[fc] = *reinterpret_cast<const bf16x8*>(
            Bs + (unsigned)(kk * 512 + (cg * 4 + fc) * 64 + lane) * 8);
      #pragma unroll
      for (int fr = 0; fr < 4; ++fr)
        #pragma unroll
        for (int fc = 0; fc < 4; ++fc)
          acc[fr][fc] = __builtin_amdgcn_mfma_f32_16x16x32_bf16(
              a[fr], b[fc], acc[fr][fc], 0, 0, 0);
    }
    if (s < 3) __syncthreads();
  }

  const int quad = lane >> 4, lc = lane & 15;

  // Diagonal extraction: row_local = fr*16+quad*4+reg, col_local = fc*16+lc.
  if (bR == bC && rg == cg) {
    #pragma unroll
    for (int fr = 0; fr < 4; ++fr)
      #pragma unroll
      for (int r = 0; r < 4; ++r)
        if (lc == quad * 4 + r)
          diag[bR * 128 + rg * 64 + fr * 16 + lc] = acc[fr][fr][r];
  }

  // Per-row partials over this wave's 64 cols. Each (fr,r) pair: 4 quads hold
  // 4 distinct rows; reduce across the 16 lc lanes (xor 1,2,4,8 stays in quad).
  #pragma unroll
  for (int fr = 0; fr < 4; ++fr) {
    #pragma unroll
    for (int r = 0; r < 4; ++r) {
      float v0 = acc[fr][0][r], v1 = acc[fr][1][r];
      float v2 = acc[fr][2][r], v3 = acc[fr][3][r];
      float m = fmaxf(fmaxf(v0, v1), fmaxf(v2, v3));
      #pragma unroll
      for (int sh = 1; sh < 16; sh <<= 1) m = fmaxf(m, __shfl_xor(m, sh, 64));
      float ss = __expf(v0 - m) + __expf(v1 - m) +
                 __expf(v2 - m) + __expf(v3 - m);
      #pragma unroll
      for (int sh = 1; sh < 16; sh <<= 1) ss += __shfl_xor(ss, sh, 64);
      if (lc == 0) {
        int grow = bR * 128 + rg * 64 + fr * 16 + quad * 4 + r;
        int p = grow * 64 + bC * 2 + cg;
        pmax[p] = m; psum[p] = ss;
      }
    }
  }
}

// ---------------------------------------------------------------------------
// K2: per-row combine of 64 col-group partials -> loss/correct, block-reduce.
// correct = (diag == global row max): argmax value IS the max; exact-fp tie
// with a non-diagonal column has measure zero.
// ---------------------------------------------------------------------------
__global__ __launch_bounds__(256) void combine_rows(
    const float* __restrict__ pmax, const float* __restrict__ psum,
    const float* __restrict__ diag,
    float* __restrict__ lpart, float* __restrict__ cpart) {
  int row = blockIdx.x * 256 + threadIdx.x;
  const float* pm = pmax + row * 64;
  const float* ps = psum + row * 64;
  float M = -3.4e38f;
  #pragma unroll 8
  for (int b = 0; b < 64; ++b) M = fmaxf(M, pm[b]);
  float S = 0.f;
  #pragma unroll 8
  for (int b = 0; b < 64; ++b) S += ps[b] * __expf(pm[b] - M);
  float d = diag[row];
  float lossr = logf(S) + M - d;
  float corr = (d == M) ? 1.f : 0.f;
  #pragma unroll
  for (int sh = 1; sh < 64; sh <<= 1) {
    lossr += __shfl_xor(lossr, sh, 64);
    corr  += __shfl_xor(corr,  sh, 64);
  }
  __shared__ float ls[4], cs[4];
  int wave = threadIdx.x >> 6, lane = threadIdx.x & 63;
  if (lane == 0) { ls[wave] = lossr; cs[wave] = corr; }
  __syncthreads();
  if (threadIdx.x == 0) {
    lpart[blockIdx.x] = ls[0] + ls[1] + ls[2] + ls[3];
    cpart[blockIdx.x] = cs[0] + cs[1] + cs[2] + cs[3];
  }
}

__global__ void finalize(const float* __restrict__ lpart,
                         const float* __restrict__ cpart,
                         float* __restrict__ out) {
  int t = threadIdx.x;
  float l = (t < 16) ? lpart[t] : 0.f;
  float c = (t < 16) ? cpart[t] : 0.f;
  #pragma unroll
  for (int sh = 1; sh < 16; sh <<= 1) {
    l += __shfl_xor(l, sh, 64);
    c += __shfl_xor(c, sh, 64);
  }
  if (t == 0) {
    out[0] = l * (1.f / 4096.f);
    out[1] = c * (100.f / 4096.f);
  }
}

extern "C" void kernel_launch(void* const* d_in, const int* in_sizes, int n_in,
                              void* d_out, int out_size, void* d_ws, size_t ws_size,
                              hipStream_t stream) {
  const float* pred = (const float*)d_in[0];
  const float* gt   = (const float*)d_in[1];
  char* w = (char*)d_ws;
  unsigned short* Xbf = (unsigned short*)(w + OFF_X);
  unsigned short* Ybf = (unsigned short*)(w + OFF_Y);
  float* pmax  = (float*)(w + OFF_PMAX);
  float* psum  = (float*)(w + OFF_PSUM);
  float* diag  = (float*)(w + OFF_DIAG);
  float* lpart = (float*)(w + OFF_LPART);
  float* cpart = (float*)(w + OFF_CPART);
  float* out   = (float*)d_out;

  transpose_stage<<<512, 256, 0, stream>>>(pred, gt, Xbf, Ybf);
  dim3 g1(32, 32);
  gemm_softmax_partial<<<g1, 256, 0, stream>>>(Xbf, Ybf, pmax, psum, diag);
  combine_rows<<<16, 256, 0, stream>>>(pmax, psum, diag, lpart, cpart);
  finalize<<<1, 64, 0, stream>>>(lpart, cpart, out);
}